// Round 5
// baseline (466.000 us; speedup 1.0000x reference)
//
#include <hip/hip_runtime.h>
#include <stdint.h>

#define HID 256
#define RNUM 6
#define NNODE 40000
#define NEVENT 20000
#define NEDGE 200000
#define NKEY (NNODE*RNUM)      // 240000
#define KCAT 1792              // 6*256 + 256 (z row width / Wall N-dim)
#define EPSV 1e-5f

typedef unsigned short u16;
typedef unsigned int u32;
typedef __attribute__((ext_vector_type(4))) float f32x4;
typedef __attribute__((ext_vector_type(4))) unsigned short u16x4;
typedef __attribute__((ext_vector_type(8))) unsigned short u16x8;
typedef __attribute__((ext_vector_type(8))) __bf16 bf16x8;

__device__ __forceinline__ float bf2f(u16 h) {
  union { u32 u; float f; } c; c.u = ((u32)h) << 16; return c.f;
}
__device__ __forceinline__ u16 f2bf(float f) {
  union { float f; u32 u; } c; c.f = f;
  return (u16)((c.u + 0x7fffu + ((c.u >> 16) & 1u)) >> 16);
}

// ---------------- CSR build ----------------

__global__ void count_keys(const int* __restrict__ dst, const int* __restrict__ typ,
                           int* __restrict__ cnt) {
  int e = blockIdx.x * blockDim.x + threadIdx.x;
  if (e >= NEDGE) return;
  atomicAdd(&cnt[dst[e] * RNUM + typ[e]], 1);
}

__global__ __launch_bounds__(256) void scan1(const int* __restrict__ cnt,
                                             int* __restrict__ offs,
                                             int* __restrict__ blockSums) {
  __shared__ int wsum[4];
  int t = threadIdx.x, b = blockIdx.x;
  int base = b * 1024 + t * 4;
  int v[4];
#pragma unroll
  for (int j = 0; j < 4; ++j) v[j] = (base + j < NKEY) ? cnt[base + j] : 0;
  int s = v[0] + v[1] + v[2] + v[3];
  int inc = s;
  int lane = t & 63, wv = t >> 6;
#pragma unroll
  for (int d = 1; d < 64; d <<= 1) {
    int o = __shfl_up(inc, d, 64);
    if (lane >= d) inc += o;
  }
  if (lane == 63) wsum[wv] = inc;
  __syncthreads();
  int wpre = 0;
  for (int w = 0; w < wv; ++w) wpre += wsum[w];
  int exc = wpre + inc - s;
  int run = exc;
#pragma unroll
  for (int j = 0; j < 4; ++j) {
    if (base + j < NKEY) offs[base + j] = run;
    run += v[j];
  }
  if (t == 255) blockSums[b] = wpre + inc;
}

__global__ void scan2(const int* __restrict__ blockSums, int* __restrict__ blockOff,
                      int nb, int* __restrict__ offs_last) {
  if (threadIdx.x == 0 && blockIdx.x == 0) {
    int run = 0;
    for (int i = 0; i < nb; ++i) { int c = blockSums[i]; blockOff[i] = run; run += c; }
    *offs_last = run;
  }
}

__global__ __launch_bounds__(256) void scan3(int* __restrict__ offs,
                                             const int* __restrict__ blockOff) {
  int t = threadIdx.x, b = blockIdx.x;
  int add = blockOff[b];
  int base = b * 1024 + t * 4;
#pragma unroll
  for (int j = 0; j < 4; ++j)
    if (base + j < NKEY) offs[base + j] += add;
}

__global__ void scatter_edges(const int* __restrict__ src, const int* __restrict__ dst,
                              const int* __restrict__ typ, const float* __restrict__ w,
                              const int* __restrict__ offs, int* __restrict__ tmpc,
                              int* __restrict__ sortedSrc, float* __restrict__ sortedW) {
  int e = blockIdx.x * blockDim.x + threadIdx.x;
  if (e >= NEDGE) return;
  int key = dst[e] * RNUM + typ[e];
  int pos = offs[key] + atomicAdd(&tmpc[key], 1);
  sortedSrc[pos] = src[e];
  sortedW[pos] = w[e];
}

// ---------------- fused setup: cvt_x | projWt | wall | arel ----------------

#define SM_R0 (NNODE*32)                 // 1,280,000 quads of x
#define SM_R1 (SM_R0 + 4*256*128)        // +131,072 projWt elems
#define SM_R2 (SM_R1 + 3*KCAT*256)       // +1,376,256 wall elems
#define SM_R3 (SM_R2 + RNUM*HID + HID)   // +1,792 arel/V elems

__global__ void setup_misc(const float* __restrict__ xe, const float* __restrict__ xf,
                           const float* __restrict__ xp, const float* __restrict__ xi,
                           u16* __restrict__ xbf,
                           const float* __restrict__ pw, u16* __restrict__ projWt,
                           const float* __restrict__ basis, const float* __restrict__ comp,
                           const float* __restrict__ root, u16* __restrict__ wall,
                           const float* __restrict__ ete, const float* __restrict__ emlpW,
                           const float* __restrict__ emlpb,
                           float* __restrict__ Arel, float* __restrict__ V) {
  int i = blockIdx.x * blockDim.x + threadIdx.x;
  if (i < SM_R0) {
    int e = i * 4;
    int row = e >> 7, col = e & 127;
    const float* srcp; int lr;
    if (row < 20000)      { srcp = xe; lr = row; }
    else if (row < 30000) { srcp = xf; lr = row - 20000; }
    else if (row < 38000) { srcp = xp; lr = row - 30000; }
    else                  { srcp = xi; lr = row - 38000; }
    f32x4 v = *(const f32x4*)&srcp[(size_t)lr * 128 + col];
    u16x4 o = { f2bf(v[0]), f2bf(v[1]), f2bf(v[2]), f2bf(v[3]) };
    *(u16x4*)&xbf[e] = o;
  } else if (i < SM_R1) {
    int j = i - SM_R0;
    int t = j >> 15, rem = j & 32767, n = rem >> 7, k = rem & 127;
    (void)n;
    projWt[j] = f2bf(pw[((size_t)t * 128 + k) * 256 + (rem >> 7)]);
  } else if (i < SM_R2) {
    int j = i - SM_R1;
    int l = j / (KCAT * 256);
    int rem = j - l * KCAT * 256;
    int og = rem >> 8;
    int k = rem & 255;
    float s;
    if (og < 1536) {
      int r = og >> 8, o = og & 255;
      s = 0.f;
#pragma unroll
      for (int b = 0; b < 8; ++b)
        s += comp[((size_t)l * 6 + r) * 8 + b] *
             basis[(((size_t)l * 8 + b) * 256 + k) * 256 + o];
    } else {
      s = root[((size_t)l * 256 + k) * 256 + (og - 1536)];
    }
    wall[j] = f2bf(s);
  } else if (i < SM_R3) {
    int j = i - SM_R2;
    if (j < RNUM * HID) {
      int r = j >> 8, c = j & 255;
      float s = emlpb[c];
#pragma unroll
      for (int k = 0; k < 16; ++k) s += ete[r * 16 + k] * emlpW[k * 256 + c];
      Arel[j] = s;
    } else {
      V[j - RNUM * HID] = emlpW[16 * 256 + (j - RNUM * HID)];
    }
  }
}

// ---------------- GEMM (BK=64): C[M,N] = A[M,K] x Bt[N,K], bf16 in ----------------
// MODE 0: main layer GEMM — XCD-remapped grid, bf16 out via LDS-packed store
// MODE 1: proj GEMM — type-batched grid (4 weight matrices), fp32 out

template <int MODE>
__global__ __launch_bounds__(256) void gemm64(const u16* __restrict__ A, int lda,
                                              const u16* __restrict__ Bt, int ldb,
                                              void* __restrict__ Cv, int ldc,
                                              int M, int Ndim, int Kdim) {
  __shared__ __align__(16) u16 As[2][128 * 64];
  __shared__ __align__(16) u16 Bs[2][128 * 64];

  int m0, n0, rowLim;
  const u16* Bp = Bt;
  if constexpr (MODE == 0) {
    const int NT = Ndim >> 7;           // 14
    const int MT = (M + 127) >> 7;      // 313
    const int chunk = (MT + 7) >> 3;    // 40
    int bid = blockIdx.x;
    int xcd = bid & 7, slot = bid >> 3;
    int mt = xcd * chunk + slot / NT;
    if (mt >= MT) return;
    m0 = mt * 128;
    n0 = (slot % NT) * 128;
    rowLim = M;
  } else {
    int bid = blockIdx.x;
    int nt = bid & 1, ms = bid >> 1;
    int t = (ms >= 157) + (ms >= 236) + (ms >= 299);
    int cum  = t == 0 ? 0     : (t == 1 ? 157   : (t == 2 ? 236   : 299));
    int row0 = t == 0 ? 0     : (t == 1 ? 20000 : (t == 2 ? 30000 : 38000));
    rowLim   = t == 0 ? 20000 : (t == 1 ? 30000 : (t == 2 ? 38000 : 40000));
    m0 = row0 + (ms - cum) * 128;
    n0 = nt * 128;
    Bp = Bt + (size_t)t * 256 * 128;
  }

  const int tid = threadIdx.x;
  const int v = tid >> 6, lane = tid & 63;
  const int wm = (v >> 1) * 64, wn = (v & 1) * 64;

  f32x4 acc[4][4];
#pragma unroll
  for (int i = 0; i < 4; ++i)
#pragma unroll
    for (int j = 0; j < 4; ++j) acc[i][j] = f32x4{0.f, 0.f, 0.f, 0.f};

  const int nk = Kdim >> 6;

  auto stage = [&](int kt, int buf) {
    const int k0 = kt << 6;
#pragma unroll
    for (int it = 0; it < 4; ++it) {
      int c = it * 256 + tid;          // 1024 16B-chunks per matrix
      int row = c >> 3, seg = c & 7;
      int ar = m0 + row; if (ar >= rowLim) ar = rowLim - 1;   // clamp (masked on store)
      const u16* ga = A + (size_t)ar * lda + k0 + seg * 8;
      __builtin_amdgcn_global_load_lds(
          (const __attribute__((address_space(1))) void*)ga,
          (__attribute__((address_space(3))) void*)(&As[buf][c * 8]),
          16, 0, 0);
      int br = n0 + row;                                      // always < Ndim
      const u16* gb = Bp + (size_t)br * ldb + k0 + seg * 8;
      __builtin_amdgcn_global_load_lds(
          (const __attribute__((address_space(1))) void*)gb,
          (__attribute__((address_space(3))) void*)(&Bs[buf][c * 8]),
          16, 0, 0);
    }
  };

  stage(0, 0);
  for (int kt = 0; kt < nk; ++kt) {
    __syncthreads();                       // stage(kt) complete, prior reads drained
    if (kt + 1 < nk) stage(kt + 1, (kt + 1) & 1);
    const u16* as = &As[kt & 1][0];
    const u16* bs = &Bs[kt & 1][0];
#pragma unroll
    for (int kk = 0; kk < 2; ++kk) {
      bf16x8 af[4], bfr[4];
#pragma unroll
      for (int mi = 0; mi < 4; ++mi)
        af[mi] = *(const bf16x8*)&as[(wm + mi * 16 + (lane & 15)) * 64 + kk * 32 + (lane >> 4) * 8];
#pragma unroll
      for (int ni = 0; ni < 4; ++ni)
        bfr[ni] = *(const bf16x8*)&bs[(wn + ni * 16 + (lane & 15)) * 64 + kk * 32 + (lane >> 4) * 8];
#pragma unroll
      for (int mi = 0; mi < 4; ++mi)
#pragma unroll
        for (int ni = 0; ni < 4; ++ni)
          acc[mi][ni] = __builtin_amdgcn_mfma_f32_16x16x32_bf16(af[mi], bfr[ni],
                                                                acc[mi][ni], 0, 0, 0);
    }
  }

  const int rr = (lane >> 4) * 4;
  const int cc = lane & 15;
  if constexpr (MODE == 0) {
    // packed bf16 store via LDS transpose (reuse As as 128x128 u16 scratch)
    __syncthreads();
    u16* scratch = &As[0][0];
#pragma unroll
    for (int mi = 0; mi < 4; ++mi)
#pragma unroll
      for (int reg = 0; reg < 4; ++reg) {
        int row = wm + mi * 16 + rr + reg;
        int swz = ((row >> 2) & 3) << 3;
#pragma unroll
        for (int ni = 0; ni < 4; ++ni)
          scratch[row * 128 + ((wn + ni * 16 + cc) ^ swz)] = f2bf(acc[mi][ni][reg]);
      }
    __syncthreads();
    u16* zc = (u16*)Cv;
#pragma unroll
    for (int it = 0; it < 8; ++it) {
      int row = it * 16 + (tid >> 4);
      int colr = (tid & 15) * 8;
      int grow = m0 + row;
      if (grow < M) {
        int swz = ((row >> 2) & 3) << 3;
        u16x8 vv = *(const u16x8*)&scratch[row * 128 + (colr ^ swz)];
        *(u16x8*)&zc[(size_t)grow * ldc + n0 + colr] = vv;
      }
    }
  } else {
    float* Cf = (float*)Cv;
#pragma unroll
    for (int mi = 0; mi < 4; ++mi) {
#pragma unroll
      for (int reg = 0; reg < 4; ++reg) {
        int row = m0 + wm + mi * 16 + rr + reg;
        if (row >= rowLim) continue;
#pragma unroll
        for (int ni = 0; ni < 4; ++ni)
          Cf[(size_t)row * ldc + n0 + wn + ni * 16 + cc] = acc[mi][ni][reg];
      }
    }
  }
}

// ---------------- fused proj LN + edge_bias (one dispatch) ----------------

__global__ __launch_bounds__(256) void node_prep(const float* __restrict__ y,
                                                 const float* __restrict__ pb,
                                                 const float* __restrict__ pg,
                                                 const float* __restrict__ pbeta,
                                                 u16* __restrict__ h_bf,
                                                 const int* __restrict__ offs,
                                                 const float* __restrict__ sortedW,
                                                 const float* __restrict__ Arel,
                                                 const float* __restrict__ V,
                                                 u16* __restrict__ ebias) {
  int wid = (blockIdx.x * blockDim.x + threadIdx.x) >> 6;
  int lane = threadIdx.x & 63;
  if (wid < NNODE) {
    int t = wid < 20000 ? 0 : (wid < 30000 ? 1 : (wid < 38000 ? 2 : 3));
    size_t base = (size_t)wid * HID + lane * 4;
    int pbase = t * HID + lane * 4;
    f32x4 x = *(const f32x4*)&y[base];
    f32x4 bv0 = *(const f32x4*)&pb[pbase];
    x += bv0;
    float s = x[0] + x[1] + x[2] + x[3];
    float s2 = x[0] * x[0] + x[1] * x[1] + x[2] * x[2] + x[3] * x[3];
#pragma unroll
    for (int d = 1; d < 64; d <<= 1) { s += __shfl_xor(s, d, 64); s2 += __shfl_xor(s2, d, 64); }
    float mean = s * (1.f / HID);
    float var = s2 * (1.f / HID) - mean * mean;
    float rs = rsqrtf(var + EPSV);
    f32x4 gv = *(const f32x4*)&pg[pbase];
    f32x4 bv = *(const f32x4*)&pbeta[pbase];
    u16x4 hb;
#pragma unroll
    for (int j = 0; j < 4; ++j) {
      float tv = (x[j] - mean) * rs * gv[j] + bv[j];
      tv = tv > 0.f ? tv : 0.f;
      hb[j] = f2bf(tv);
    }
    *(u16x4*)&h_bf[base] = hb;
  } else if (wid < 2 * NNODE) {
    int n = wid - NNODE;
    f32x4 vv = *(const f32x4*)&V[lane * 4];
    f32x4 acc = {0.f, 0.f, 0.f, 0.f};
    int beg0 = offs[n * RNUM];
#pragma unroll
    for (int r = 0; r < RNUM; ++r) {
      int b0 = offs[n * RNUM + r], b1 = offs[n * RNUM + r + 1];
      if (b0 == b1) continue;
      f32x4 av = *(const f32x4*)&Arel[r * HID + lane * 4];
      for (int p = b0; p < b1; ++p) {
        float wv = sortedW[p];
#pragma unroll
        for (int j = 0; j < 4; ++j) {
          float t = av[j] + wv * vv[j];
          acc[j] += t > 0.f ? t : 0.f;
        }
      }
    }
    int deg = offs[n * RNUM + RNUM] - beg0;
    float sc = 0.1f / (float)(deg > 1 ? deg : 1);
    u16x4 o = { f2bf(acc[0] * sc), f2bf(acc[1] * sc), f2bf(acc[2] * sc), f2bf(acc[3] * sc) };
    *(u16x4*)&ebias[(size_t)n * HID + lane * 4] = o;
  }
}

// ---------------- fused aggregation + epilogue (per layer) ----------------

__global__ __launch_bounds__(256) void agg_epilogue(const u16* __restrict__ z,
                                                    const int* __restrict__ offs,
                                                    const int* __restrict__ sortedSrc,
                                                    const u16* __restrict__ ebias,
                                                    const float* __restrict__ cb,
                                                    const float* __restrict__ g,
                                                    const float* __restrict__ b,
                                                    u16* __restrict__ h_bf,
                                                    float* __restrict__ outp) {
  int n = (blockIdx.x * blockDim.x + threadIdx.x) >> 6;
  int lane = threadIdx.x & 63;
  if (n >= NNODE) return;
  int col = lane * 4;
  int bo[7];
#pragma unroll
  for (int i = 0; i < 7; ++i) bo[i] = offs[n * RNUM + i];
  float inv0, inv1, inv2, inv3, inv4, inv5;
  {
    int c0 = bo[1]-bo[0], c1 = bo[2]-bo[1], c2 = bo[3]-bo[2];
    int c3 = bo[4]-bo[3], c4 = bo[5]-bo[4], c5 = bo[6]-bo[5];
    inv0 = c0 > 0 ? 1.f / (float)c0 : 0.f;
    inv1 = c1 > 0 ? 1.f / (float)c1 : 0.f;
    inv2 = c2 > 0 ? 1.f / (float)c2 : 0.f;
    inv3 = c3 > 0 ? 1.f / (float)c3 : 0.f;
    inv4 = c4 > 0 ? 1.f / (float)c4 : 0.f;
    inv5 = c5 > 0 ? 1.f / (float)c5 : 0.f;
  }
  f32x4 x = {0.f, 0.f, 0.f, 0.f};
  const int p0 = bo[0], p6 = bo[6];
  for (int p = p0; p < p6; p += 4) {
    int m = p6 - p; if (m > 4) m = 4;
    u16x4 zv[4]; float iv[4];
#pragma unroll
    for (int t = 0; t < 4; ++t) {
      if (t < m) {
        int pe = p + t;
        int roff = 0;
        float ivv = inv0;
        if (pe >= bo[1]) { roff = 256;  ivv = inv1; }
        if (pe >= bo[2]) { roff = 512;  ivv = inv2; }
        if (pe >= bo[3]) { roff = 768;  ivv = inv3; }
        if (pe >= bo[4]) { roff = 1024; ivv = inv4; }
        if (pe >= bo[5]) { roff = 1280; ivv = inv5; }
        int src = sortedSrc[pe];
        zv[t] = *(const u16x4*)&z[(size_t)src * KCAT + roff + col];
        iv[t] = ivv;
      }
    }
#pragma unroll
    for (int t = 0; t < 4; ++t) {
      if (t < m) {
#pragma unroll
        for (int j = 0; j < 4; ++j) x[j] += bf2f(zv[t][j]) * iv[t];
      }
    }
  }
  u16x4 zr = *(const u16x4*)&z[(size_t)n * KCAT + 1536 + col];
  u16x4 eb = *(const u16x4*)&ebias[(size_t)n * HID + col];
  f32x4 cbv = *(const f32x4*)&cb[col];
#pragma unroll
  for (int j = 0; j < 4; ++j) x[j] += bf2f(zr[j]) + cbv[j] + bf2f(eb[j]);
  float s = x[0] + x[1] + x[2] + x[3];
  float s2 = x[0] * x[0] + x[1] * x[1] + x[2] * x[2] + x[3] * x[3];
#pragma unroll
  for (int d = 1; d < 64; d <<= 1) { s += __shfl_xor(s, d, 64); s2 += __shfl_xor(s2, d, 64); }
  float mean = s * (1.f / HID);
  float var = s2 * (1.f / HID) - mean * mean;
  float rs = rsqrtf(var + EPSV);
  f32x4 gv = *(const f32x4*)&g[col];
  f32x4 bv = *(const f32x4*)&b[col];
  size_t base = (size_t)n * HID + col;
  u16x4 hold = *(const u16x4*)&h_bf[base];
  u16x4 hb; f32x4 r;
#pragma unroll
  for (int j = 0; j < 4; ++j) {
    float tv = (x[j] - mean) * rs * gv[j] + bv[j];
    tv = tv > 0.f ? tv : 0.f;
    r[j] = tv + bf2f(hold[j]);
    hb[j] = f2bf(r[j]);
  }
  *(u16x4*)&h_bf[base] = hb;
  if (outp != nullptr && n < NEVENT) *(f32x4*)&outp[base] = r;
}

// ---------------- launch ----------------

extern "C" void kernel_launch(void* const* d_in, const int* in_sizes, int n_in,
                              void* d_out, int out_size, void* d_ws, size_t ws_size,
                              hipStream_t stream) {
  const float* x_event = (const float*)d_in[0];
  const float* x_file  = (const float*)d_in[1];
  const float* x_proc  = (const float*)d_in[2];
  const float* x_ip    = (const float*)d_in[3];
  const int*   e_src   = (const int*)d_in[4];
  const int*   e_dst   = (const int*)d_in[5];
  const int*   e_typ   = (const int*)d_in[6];
  const float* e_w     = (const float*)d_in[7];
  const float* proj_W  = (const float*)d_in[8];
  const float* proj_b  = (const float*)d_in[9];
  const float* proj_g  = (const float*)d_in[10];
  const float* proj_be = (const float*)d_in[11];
  const float* ete     = (const float*)d_in[12];
  const float* emlpW   = (const float*)d_in[13];
  const float* emlpb   = (const float*)d_in[14];
  const float* basis   = (const float*)d_in[15];
  const float* comp    = (const float*)d_in[16];
  const float* root    = (const float*)d_in[17];
  const float* convb   = (const float*)d_in[18];
  const float* ln_g    = (const float*)d_in[19];
  const float* ln_b    = (const float*)d_in[20];
  float* outp = (float*)d_out;

  char* p = (char*)d_ws;
  auto alloc = [&](size_t bytes) {
    char* r = p; p += (bytes + 255) & ~(size_t)255; return r;
  };
  u16*   z       = (u16*)  alloc((size_t)NNODE * KCAT * 2);   // 143.4 MB
  u16*   h_bf    = (u16*)  alloc((size_t)NNODE * HID * 2);    // 20.5 MB
  u16*   ebias   = (u16*)  alloc((size_t)NNODE * HID * 2);    // 20.5 MB
  u16*   xbf     = (u16*)  alloc((size_t)NNODE * 128 * 2);    // 10.3 MB
  u16*   projWt  = (u16*)  alloc((size_t)4 * HID * 128 * 2);
  u16*   WallT   = (u16*)  alloc((size_t)3 * KCAT * 256 * 2); // 2.75 MB
  float* Arel    = (float*)alloc(6 * HID * 4);
  float* Vv      = (float*)alloc(HID * 4);
  int*   cnt     = (int*)  alloc(NKEY * 4);
  int*   tmpc    = (int*)  alloc(NKEY * 4);
  int*   offs    = (int*)  alloc((NKEY + 1) * 4);
  int*   bSums   = (int*)  alloc(256 * 4);
  int*   bOff    = (int*)  alloc(256 * 4);
  int*   sSrc    = (int*)  alloc((size_t)NEDGE * 4);
  float* sW      = (float*)alloc((size_t)NEDGE * 4);
  float* y       = (float*)z;   // alias: y (proj output, 41 MB fp32) dead before z written
  (void)in_sizes; (void)n_in; (void)out_size; (void)ws_size;

  const int NB1 = (NKEY + 1023) / 1024;  // 235

  hipMemsetAsync(cnt, 0, (size_t)NKEY * 4, stream);
  hipMemsetAsync(tmpc, 0, (size_t)NKEY * 4, stream);
  count_keys<<<(NEDGE + 255) / 256, 256, 0, stream>>>(e_dst, e_typ, cnt);
  scan1<<<NB1, 256, 0, stream>>>(cnt, offs, bSums);
  scan2<<<1, 1, 0, stream>>>(bSums, bOff, NB1, offs + NKEY);
  scan3<<<NB1, 256, 0, stream>>>(offs, bOff);
  scatter_edges<<<(NEDGE + 255) / 256, 256, 0, stream>>>(e_src, e_dst, e_typ, e_w,
                                                         offs, tmpc, sSrc, sW);

  setup_misc<<<(SM_R3 + 255) / 256, 256, 0, stream>>>(
      x_event, x_file, x_proc, x_ip, xbf, proj_W, projWt,
      basis, comp, root, WallT, ete, emlpW, emlpb, Arel, Vv);

  // batched per-type input projection (single dispatch, 630 blocks)
  gemm64<1><<<630, 256, 0, stream>>>(xbf, 128, projWt, 128, y, HID,
                                     NNODE, 256, 128);
  node_prep<<<(2 * NNODE * 64) / 256, 256, 0, stream>>>(
      y, proj_b, proj_g, proj_be, h_bf, offs, sW, Arel, Vv, ebias);

  // main-GEMM grid: XCD-remapped 1D; MT=313, NT=14, chunk=40 -> 8*40*14 = 4480
  const int MT = (NNODE + 127) / 128, NT = KCAT / 128;
  const int chunk = (MT + 7) / 8;
  const int nblk = 8 * chunk * NT;
  for (int l = 0; l < 3; ++l) {
    gemm64<0><<<nblk, 256, 0, stream>>>(h_bf, HID,
                                        WallT + (size_t)l * KCAT * 256, 256,
                                        z, KCAT, NNODE, KCAT, 256);
    agg_epilogue<<<(NNODE * 64 + 255) / 256, 256, 0, stream>>>(
        z, offs, sSrc, ebias, convb + l * HID, ln_g + l * HID, ln_b + l * HID,
        h_bf, (l == 2) ? outp : nullptr);
  }
}

// Round 6
// 392.951 us; speedup vs baseline: 1.1859x; 1.1859x over previous
//
#include <hip/hip_runtime.h>
#include <stdint.h>

#define HID 256
#define RNUM 6
#define NNODE 40000
#define NEVENT 20000
#define NEDGE 200000
#define NKEY (NNODE*RNUM)      // 240000
#define KCAT 1792              // 6*256 + 256 (z row width / Wall N-dim)
#define EPSV 1e-5f

typedef unsigned short u16;
typedef unsigned int u32;
typedef __attribute__((ext_vector_type(4))) float f32x4;
typedef __attribute__((ext_vector_type(4))) unsigned short u16x4;
typedef __attribute__((ext_vector_type(8))) unsigned short u16x8;
typedef __attribute__((ext_vector_type(8))) __bf16 bf16x8;

__device__ __forceinline__ float bf2f(u16 h) {
  union { u32 u; float f; } c; c.u = ((u32)h) << 16; return c.f;
}
__device__ __forceinline__ u16 f2bf(float f) {
  union { float f; u32 u; } c; c.f = f;
  return (u16)((c.u + 0x7fffu + ((c.u >> 16) & 1u)) >> 16);
}

// ---------------- CSR build ----------------

__global__ void count_keys(const int* __restrict__ dst, const int* __restrict__ typ,
                           int* __restrict__ cnt) {
  int e = blockIdx.x * blockDim.x + threadIdx.x;
  if (e >= NEDGE) return;
  atomicAdd(&cnt[dst[e] * RNUM + typ[e]], 1);
}

__global__ __launch_bounds__(256) void scan1(const int* __restrict__ cnt,
                                             int* __restrict__ offs,
                                             int* __restrict__ blockSums) {
  __shared__ int wsum[4];
  int t = threadIdx.x, b = blockIdx.x;
  int base = b * 1024 + t * 4;
  int v[4];
#pragma unroll
  for (int j = 0; j < 4; ++j) v[j] = (base + j < NKEY) ? cnt[base + j] : 0;
  int s = v[0] + v[1] + v[2] + v[3];
  int inc = s;
  int lane = t & 63, wv = t >> 6;
#pragma unroll
  for (int d = 1; d < 64; d <<= 1) {
    int o = __shfl_up(inc, d, 64);
    if (lane >= d) inc += o;
  }
  if (lane == 63) wsum[wv] = inc;
  __syncthreads();
  int wpre = 0;
  for (int w = 0; w < wv; ++w) wpre += wsum[w];
  int exc = wpre + inc - s;
  int run = exc;
#pragma unroll
  for (int j = 0; j < 4; ++j) {
    if (base + j < NKEY) offs[base + j] = run;
    run += v[j];
  }
  if (t == 255) blockSums[b] = wpre + inc;
}

// single-block parallel scan of up to 256 block sums
__global__ __launch_bounds__(256) void scan2(const int* __restrict__ blockSums,
                                             int* __restrict__ blockOff,
                                             int nb, int* __restrict__ offs_last) {
  __shared__ int wsum[4];
  int t = threadIdx.x;
  int v = t < nb ? blockSums[t] : 0;
  int inc = v;
  int lane = t & 63, wv = t >> 6;
#pragma unroll
  for (int d = 1; d < 64; d <<= 1) {
    int o = __shfl_up(inc, d, 64);
    if (lane >= d) inc += o;
  }
  if (lane == 63) wsum[wv] = inc;
  __syncthreads();
  int wpre = 0;
  for (int w = 0; w < wv; ++w) wpre += wsum[w];
  if (t < nb) blockOff[t] = wpre + inc - v;
  if (t == 255) *offs_last = wpre + inc;
}

__global__ __launch_bounds__(256) void scan3(int* __restrict__ offs,
                                             const int* __restrict__ blockOff) {
  int t = threadIdx.x, b = blockIdx.x;
  int add = blockOff[b];
  int base = b * 1024 + t * 4;
#pragma unroll
  for (int j = 0; j < 4; ++j)
    if (base + j < NKEY) offs[base + j] += add;
}

__global__ void scatter_edges(const int* __restrict__ src, const int* __restrict__ dst,
                              const int* __restrict__ typ, const float* __restrict__ w,
                              const int* __restrict__ offs, int* __restrict__ tmpc,
                              int* __restrict__ sortedSrc, float* __restrict__ sortedW) {
  int e = blockIdx.x * blockDim.x + threadIdx.x;
  if (e >= NEDGE) return;
  int key = dst[e] * RNUM + typ[e];
  int pos = offs[key] + atomicAdd(&tmpc[key], 1);
  sortedSrc[pos] = src[e];
  sortedW[pos] = w[e];
}

// ---------------- fused setup: cvt_x | projWt | wall | arel ----------------

#define SM_R0 (NNODE*32)                 // 1,280,000 quads of x
#define SM_R1 (SM_R0 + 4*256*128)        // +131,072 projWt elems
#define SM_R2 (SM_R1 + 3*KCAT*256)       // +1,376,256 wall elems
#define SM_R3 (SM_R2 + RNUM*HID + HID)   // +1,792 arel/V elems

__global__ void setup_misc(const float* __restrict__ xe, const float* __restrict__ xf,
                           const float* __restrict__ xp, const float* __restrict__ xi,
                           u16* __restrict__ xbf,
                           const float* __restrict__ pw, u16* __restrict__ projWt,
                           const float* __restrict__ basis, const float* __restrict__ comp,
                           const float* __restrict__ root, u16* __restrict__ wall,
                           const float* __restrict__ ete, const float* __restrict__ emlpW,
                           const float* __restrict__ emlpb,
                           float* __restrict__ Arel, float* __restrict__ V) {
  int i = blockIdx.x * blockDim.x + threadIdx.x;
  if (i < SM_R0) {
    int e = i * 4;
    int row = e >> 7, col = e & 127;
    const float* srcp; int lr;
    if (row < 20000)      { srcp = xe; lr = row; }
    else if (row < 30000) { srcp = xf; lr = row - 20000; }
    else if (row < 38000) { srcp = xp; lr = row - 30000; }
    else                  { srcp = xi; lr = row - 38000; }
    f32x4 v = *(const f32x4*)&srcp[(size_t)lr * 128 + col];
    u16x4 o = { f2bf(v[0]), f2bf(v[1]), f2bf(v[2]), f2bf(v[3]) };
    *(u16x4*)&xbf[e] = o;
  } else if (i < SM_R1) {
    int j = i - SM_R0;
    int t = j >> 15, rem = j & 32767, n = rem >> 7, k = rem & 127;
    projWt[j] = f2bf(pw[((size_t)t * 128 + k) * 256 + n]);
  } else if (i < SM_R2) {
    int j = i - SM_R1;
    int l = j / (KCAT * 256);
    int rem = j - l * KCAT * 256;
    int og = rem >> 8;
    int k = rem & 255;
    float s;
    if (og < 1536) {
      int r = og >> 8, o = og & 255;
      s = 0.f;
#pragma unroll
      for (int b = 0; b < 8; ++b)
        s += comp[((size_t)l * 6 + r) * 8 + b] *
             basis[(((size_t)l * 8 + b) * 256 + k) * 256 + o];
    } else {
      s = root[((size_t)l * 256 + k) * 256 + (og - 1536)];
    }
    wall[j] = f2bf(s);
  } else if (i < SM_R3) {
    int j = i - SM_R2;
    if (j < RNUM * HID) {
      int r = j >> 8, c = j & 255;
      float s = emlpb[c];
#pragma unroll
      for (int k = 0; k < 16; ++k) s += ete[r * 16 + k] * emlpW[k * 256 + c];
      Arel[j] = s;
    } else {
      V[j - RNUM * HID] = emlpW[16 * 256 + (j - RNUM * HID)];
    }
  }
}

// ---------------- GEMM (BK=32, swizzled LDS): C = A[M,K] x Bt[N,K] ----------------
// MODE 0: main layer GEMM — XCD-remapped grid, packed bf16 out via LDS scratch
// MODE 1: proj GEMM — type-batched grid (4 weight matrices), fp32 out
// LDS swizzle (rule #21 both-sides): staging loads global slot seg^((row>>1)&3)
// into linear LDS; fragment read uses slot q^((row>>1)&3). Bank map becomes
// 16*(row&1) + 4*(q^((row>>1)&3)) -> 2 lanes/bank (free).

template <int MODE>
__global__ __launch_bounds__(256) void gemm32(const u16* __restrict__ A, int lda,
                                              const u16* __restrict__ Bt, int ldb,
                                              void* __restrict__ Cv, int ldc,
                                              int M, int Ndim, int Kdim) {
  __shared__ __align__(16) u16 lds[4][128 * 32];   // As buf0/1, Bs buf0/1 (32 KB)

  int m0, n0, rowLim;
  const u16* Bp = Bt;
  if constexpr (MODE == 0) {
    const int NT = Ndim >> 7;           // 14
    const int MT = (M + 127) >> 7;      // 313
    const int chunk = (MT + 7) >> 3;    // 40
    int bid = blockIdx.x;
    int xcd = bid & 7, slot = bid >> 3;
    int mt = xcd * chunk + slot / NT;
    if (mt >= MT) return;
    m0 = mt * 128;
    n0 = (slot % NT) * 128;
    rowLim = M;
  } else {
    int bid = blockIdx.x;
    int nt = bid & 1, ms = bid >> 1;
    int t = (ms >= 157) + (ms >= 236) + (ms >= 299);
    int cum  = t == 0 ? 0     : (t == 1 ? 157   : (t == 2 ? 236   : 299));
    int row0 = t == 0 ? 0     : (t == 1 ? 20000 : (t == 2 ? 30000 : 38000));
    rowLim   = t == 0 ? 20000 : (t == 1 ? 30000 : (t == 2 ? 38000 : 40000));
    m0 = row0 + (ms - cum) * 128;
    n0 = nt * 128;
    Bp = Bt + (size_t)t * 256 * 128;
  }

  const int tid = threadIdx.x;
  const int v = tid >> 6, lane = tid & 63;
  const int wm = (v >> 1) * 64, wn = (v & 1) * 64;

  f32x4 acc[4][4];
#pragma unroll
  for (int i = 0; i < 4; ++i)
#pragma unroll
    for (int j = 0; j < 4; ++j) acc[i][j] = f32x4{0.f, 0.f, 0.f, 0.f};

  const int nk = Kdim >> 5;

  auto stage = [&](int kt, int buf) {
    const int k0 = kt << 5;
#pragma unroll
    for (int it = 0; it < 2; ++it) {
      int c = it * 256 + tid;            // 512 16B-chunks per matrix
      int row = c >> 2, seg = c & 3;
      int sseg = seg ^ ((row >> 1) & 3); // pre-swizzled global source slot
      int ar = m0 + row; if (ar >= rowLim) ar = rowLim - 1;  // clamp (masked on store)
      const u16* ga = A + (size_t)ar * lda + k0 + sseg * 8;
      __builtin_amdgcn_global_load_lds(
          (const __attribute__((address_space(1))) void*)ga,
          (__attribute__((address_space(3))) void*)(&lds[buf][c * 8]),
          16, 0, 0);
      int br = n0 + row;                                     // always < Ndim
      const u16* gb = Bp + (size_t)br * ldb + k0 + sseg * 8;
      __builtin_amdgcn_global_load_lds(
          (const __attribute__((address_space(1))) void*)gb,
          (__attribute__((address_space(3))) void*)(&lds[2 + buf][c * 8]),
          16, 0, 0);
    }
  };

  stage(0, 0);
  for (int kt = 0; kt < nk; ++kt) {
    __syncthreads();                       // stage(kt) complete, prior reads drained
    if (kt + 1 < nk) stage(kt + 1, (kt + 1) & 1);
    const u16* as = &lds[kt & 1][0];
    const u16* bs = &lds[2 + (kt & 1)][0];
    const int q = lane >> 4;
    bf16x8 af[4], bfr[4];
#pragma unroll
    for (int mi = 0; mi < 4; ++mi) {
      int row = wm + mi * 16 + (lane & 15);
      int slot = q ^ ((row >> 1) & 3);
      af[mi] = *(const bf16x8*)&as[row * 32 + slot * 8];
    }
#pragma unroll
    for (int ni = 0; ni < 4; ++ni) {
      int row = wn + ni * 16 + (lane & 15);
      int slot = q ^ ((row >> 1) & 3);
      bfr[ni] = *(const bf16x8*)&bs[row * 32 + slot * 8];
    }
#pragma unroll
    for (int mi = 0; mi < 4; ++mi)
#pragma unroll
      for (int ni = 0; ni < 4; ++ni)
        acc[mi][ni] = __builtin_amdgcn_mfma_f32_16x16x32_bf16(af[mi], bfr[ni],
                                                              acc[mi][ni], 0, 0, 0);
  }

  const int rr = (lane >> 4) * 4;
  const int cc = lane & 15;
  if constexpr (MODE == 0) {
    // packed bf16 store: acc -> LDS scratch (swizzled) -> 16B coalesced stores
    __syncthreads();
    u16* scratch = &lds[0][0];             // 128x128 u16 = 32 KB (whole LDS)
#pragma unroll
    for (int mi = 0; mi < 4; ++mi)
#pragma unroll
      for (int reg = 0; reg < 4; ++reg) {
        int row = wm + mi * 16 + rr + reg;
        int swz = ((row >> 2) & 3) << 4;
#pragma unroll
        for (int ni = 0; ni < 4; ++ni)
          scratch[row * 128 + ((wn + ni * 16 + cc) ^ swz)] = f2bf(acc[mi][ni][reg]);
      }
    __syncthreads();
    u16* zc = (u16*)Cv;
#pragma unroll
    for (int it = 0; it < 8; ++it) {
      int row = it * 16 + (tid >> 4);
      int colr = (tid & 15) * 8;
      int grow = m0 + row;
      if (grow < M) {
        int swz = ((row >> 2) & 3) << 4;
        u16x8 vv = *(const u16x8*)&scratch[row * 128 + (colr ^ swz)];
        *(u16x8*)&zc[(size_t)grow * ldc + n0 + colr] = vv;
      }
    }
  } else {
    float* Cf = (float*)Cv;
#pragma unroll
    for (int mi = 0; mi < 4; ++mi) {
#pragma unroll
      for (int reg = 0; reg < 4; ++reg) {
        int row = m0 + wm + mi * 16 + rr + reg;
        if (row >= rowLim) continue;
#pragma unroll
        for (int ni = 0; ni < 4; ++ni)
          Cf[(size_t)row * ldc + n0 + wn + ni * 16 + cc] = acc[mi][ni][reg];
      }
    }
  }
}

// ---------------- fused proj LN + edge_bias (one dispatch) ----------------

__global__ __launch_bounds__(256) void node_prep(const float* __restrict__ y,
                                                 const float* __restrict__ pb,
                                                 const float* __restrict__ pg,
                                                 const float* __restrict__ pbeta,
                                                 u16* __restrict__ h_bf,
                                                 const int* __restrict__ offs,
                                                 const float* __restrict__ sortedW,
                                                 const float* __restrict__ Arel,
                                                 const float* __restrict__ V,
                                                 u16* __restrict__ ebias) {
  int wid = (blockIdx.x * blockDim.x + threadIdx.x) >> 6;
  int lane = threadIdx.x & 63;
  if (wid < NNODE) {
    int t = wid < 20000 ? 0 : (wid < 30000 ? 1 : (wid < 38000 ? 2 : 3));
    size_t base = (size_t)wid * HID + lane * 4;
    int pbase = t * HID + lane * 4;
    f32x4 x = *(const f32x4*)&y[base];
    f32x4 bv0 = *(const f32x4*)&pb[pbase];
    x += bv0;
    float s = x[0] + x[1] + x[2] + x[3];
    float s2 = x[0] * x[0] + x[1] * x[1] + x[2] * x[2] + x[3] * x[3];
#pragma unroll
    for (int d = 1; d < 64; d <<= 1) { s += __shfl_xor(s, d, 64); s2 += __shfl_xor(s2, d, 64); }
    float mean = s * (1.f / HID);
    float var = s2 * (1.f / HID) - mean * mean;
    float rs = rsqrtf(var + EPSV);
    f32x4 gv = *(const f32x4*)&pg[pbase];
    f32x4 bv = *(const f32x4*)&pbeta[pbase];
    u16x4 hb;
#pragma unroll
    for (int j = 0; j < 4; ++j) {
      float tv = (x[j] - mean) * rs * gv[j] + bv[j];
      tv = tv > 0.f ? tv : 0.f;
      hb[j] = f2bf(tv);
    }
    *(u16x4*)&h_bf[base] = hb;
  } else if (wid < 2 * NNODE) {
    int n = wid - NNODE;
    f32x4 vv = *(const f32x4*)&V[lane * 4];
    f32x4 acc = {0.f, 0.f, 0.f, 0.f};
    int beg0 = offs[n * RNUM];
#pragma unroll
    for (int r = 0; r < RNUM; ++r) {
      int b0 = offs[n * RNUM + r], b1 = offs[n * RNUM + r + 1];
      if (b0 == b1) continue;
      f32x4 av = *(const f32x4*)&Arel[r * HID + lane * 4];
      for (int p = b0; p < b1; ++p) {
        float wv = sortedW[p];
#pragma unroll
        for (int j = 0; j < 4; ++j) {
          float t = av[j] + wv * vv[j];
          acc[j] += t > 0.f ? t : 0.f;
        }
      }
    }
    int deg = offs[n * RNUM + RNUM] - beg0;
    float sc = 0.1f / (float)(deg > 1 ? deg : 1);
    u16x4 o = { f2bf(acc[0] * sc), f2bf(acc[1] * sc), f2bf(acc[2] * sc), f2bf(acc[3] * sc) };
    *(u16x4*)&ebias[(size_t)n * HID + lane * 4] = o;
  }
}

// ---------------- fused aggregation + epilogue (per layer) ----------------

__global__ __launch_bounds__(256) void agg_epilogue(const u16* __restrict__ z,
                                                    const int* __restrict__ offs,
                                                    const int* __restrict__ sortedSrc,
                                                    const u16* __restrict__ ebias,
                                                    const float* __restrict__ cb,
                                                    const float* __restrict__ g,
                                                    const float* __restrict__ b,
                                                    u16* __restrict__ h_bf,
                                                    float* __restrict__ outp) {
  int n = (blockIdx.x * blockDim.x + threadIdx.x) >> 6;
  int lane = threadIdx.x & 63;
  if (n >= NNODE) return;
  int col = lane * 4;
  int bo[7];
#pragma unroll
  for (int i = 0; i < 7; ++i) bo[i] = offs[n * RNUM + i];
  float inv0, inv1, inv2, inv3, inv4, inv5;
  {
    int c0 = bo[1]-bo[0], c1 = bo[2]-bo[1], c2 = bo[3]-bo[2];
    int c3 = bo[4]-bo[3], c4 = bo[5]-bo[4], c5 = bo[6]-bo[5];
    inv0 = c0 > 0 ? 1.f / (float)c0 : 0.f;
    inv1 = c1 > 0 ? 1.f / (float)c1 : 0.f;
    inv2 = c2 > 0 ? 1.f / (float)c2 : 0.f;
    inv3 = c3 > 0 ? 1.f / (float)c3 : 0.f;
    inv4 = c4 > 0 ? 1.f / (float)c4 : 0.f;
    inv5 = c5 > 0 ? 1.f / (float)c5 : 0.f;
  }
  f32x4 x = {0.f, 0.f, 0.f, 0.f};
  const int p0 = bo[0], p6 = bo[6];
  for (int p = p0; p < p6; p += 4) {
    int m = p6 - p; if (m > 4) m = 4;
    u16x4 zv[4]; float iv[4];
#pragma unroll
    for (int t = 0; t < 4; ++t) {
      if (t < m) {
        int pe = p + t;
        int roff = 0;
        float ivv = inv0;
        if (pe >= bo[1]) { roff = 256;  ivv = inv1; }
        if (pe >= bo[2]) { roff = 512;  ivv = inv2; }
        if (pe >= bo[3]) { roff = 768;  ivv = inv3; }
        if (pe >= bo[4]) { roff = 1024; ivv = inv4; }
        if (pe >= bo[5]) { roff = 1280; ivv = inv5; }
        int src = sortedSrc[pe];
        zv[t] = *(const u16x4*)&z[(size_t)src * KCAT + roff + col];
        iv[t] = ivv;
      }
    }
#pragma unroll
    for (int t = 0; t < 4; ++t) {
      if (t < m) {
#pragma unroll
        for (int j = 0; j < 4; ++j) x[j] += bf2f(zv[t][j]) * iv[t];
      }
    }
  }
  u16x4 zr = *(const u16x4*)&z[(size_t)n * KCAT + 1536 + col];
  u16x4 eb = *(const u16x4*)&ebias[(size_t)n * HID + col];
  f32x4 cbv = *(const f32x4*)&cb[col];
#pragma unroll
  for (int j = 0; j < 4; ++j) x[j] += bf2f(zr[j]) + cbv[j] + bf2f(eb[j]);
  float s = x[0] + x[1] + x[2] + x[3];
  float s2 = x[0] * x[0] + x[1] * x[1] + x[2] * x[2] + x[3] * x[3];
#pragma unroll
  for (int d = 1; d < 64; d <<= 1) { s += __shfl_xor(s, d, 64); s2 += __shfl_xor(s2, d, 64); }
  float mean = s * (1.f / HID);
  float var = s2 * (1.f / HID) - mean * mean;
  float rs = rsqrtf(var + EPSV);
  f32x4 gv = *(const f32x4*)&g[col];
  f32x4 bv = *(const f32x4*)&b[col];
  size_t base = (size_t)n * HID + col;
  u16x4 hold = *(const u16x4*)&h_bf[base];
  u16x4 hb; f32x4 r;
#pragma unroll
  for (int j = 0; j < 4; ++j) {
    float tv = (x[j] - mean) * rs * gv[j] + bv[j];
    tv = tv > 0.f ? tv : 0.f;
    r[j] = tv + bf2f(hold[j]);
    hb[j] = f2bf(r[j]);
  }
  *(u16x4*)&h_bf[base] = hb;
  if (outp != nullptr && n < NEVENT) *(f32x4*)&outp[base] = r;
}

// ---------------- launch ----------------

extern "C" void kernel_launch(void* const* d_in, const int* in_sizes, int n_in,
                              void* d_out, int out_size, void* d_ws, size_t ws_size,
                              hipStream_t stream) {
  const float* x_event = (const float*)d_in[0];
  const float* x_file  = (const float*)d_in[1];
  const float* x_proc  = (const float*)d_in[2];
  const float* x_ip    = (const float*)d_in[3];
  const int*   e_src   = (const int*)d_in[4];
  const int*   e_dst   = (const int*)d_in[5];
  const int*   e_typ   = (const int*)d_in[6];
  const float* e_w     = (const float*)d_in[7];
  const float* proj_W  = (const float*)d_in[8];
  const float* proj_b  = (const float*)d_in[9];
  const float* proj_g  = (const float*)d_in[10];
  const float* proj_be = (const float*)d_in[11];
  const float* ete     = (const float*)d_in[12];
  const float* emlpW   = (const float*)d_in[13];
  const float* emlpb   = (const float*)d_in[14];
  const float* basis   = (const float*)d_in[15];
  const float* comp    = (const float*)d_in[16];
  const float* root    = (const float*)d_in[17];
  const float* convb   = (const float*)d_in[18];
  const float* ln_g    = (const float*)d_in[19];
  const float* ln_b    = (const float*)d_in[20];
  float* outp = (float*)d_out;

  char* p = (char*)d_ws;
  auto alloc = [&](size_t bytes) {
    char* r = p; p += (bytes + 255) & ~(size_t)255; return r;
  };
  u16*   z       = (u16*)  alloc((size_t)NNODE * KCAT * 2);   // 143.4 MB
  u16*   h_bf    = (u16*)  alloc((size_t)NNODE * HID * 2);    // 20.5 MB
  u16*   ebias   = (u16*)  alloc((size_t)NNODE * HID * 2);    // 20.5 MB
  u16*   xbf     = (u16*)  alloc((size_t)NNODE * 128 * 2);    // 10.3 MB
  u16*   projWt  = (u16*)  alloc((size_t)4 * HID * 128 * 2);
  u16*   WallT   = (u16*)  alloc((size_t)3 * KCAT * 256 * 2); // 2.75 MB
  float* Arel    = (float*)alloc(6 * HID * 4);
  float* Vv      = (float*)alloc(HID * 4);
  int*   cnt     = (int*)  alloc(NKEY * 4);                   // NB: contiguous with tmpc
  int*   tmpc    = (int*)  alloc(NKEY * 4);
  int*   offs    = (int*)  alloc((NKEY + 1) * 4);
  int*   bSums   = (int*)  alloc(256 * 4);
  int*   bOff    = (int*)  alloc(256 * 4);
  int*   sSrc    = (int*)  alloc((size_t)NEDGE * 4);
  float* sW      = (float*)alloc((size_t)NEDGE * 4);
  float* y       = (float*)z;   // alias: y (proj output, 41 MB fp32) dead before z written
  (void)in_sizes; (void)n_in; (void)out_size; (void)ws_size;

  const int NB1 = (NKEY + 1023) / 1024;  // 235

  hipMemsetAsync(cnt, 0, (size_t)NKEY * 8, stream);  // cnt + tmpc (adjacent)
  count_keys<<<(NEDGE + 255) / 256, 256, 0, stream>>>(e_dst, e_typ, cnt);
  scan1<<<NB1, 256, 0, stream>>>(cnt, offs, bSums);
  scan2<<<1, 256, 0, stream>>>(bSums, bOff, NB1, offs + NKEY);
  scan3<<<NB1, 256, 0, stream>>>(offs, bOff);
  scatter_edges<<<(NEDGE + 255) / 256, 256, 0, stream>>>(e_src, e_dst, e_typ, e_w,
                                                         offs, tmpc, sSrc, sW);

  setup_misc<<<(SM_R3 + 255) / 256, 256, 0, stream>>>(
      x_event, x_file, x_proc, x_ip, xbf, proj_W, projWt,
      basis, comp, root, WallT, ete, emlpW, emlpb, Arel, Vv);

  // batched per-type input projection (single dispatch, 630 blocks)
  gemm32<1><<<630, 256, 0, stream>>>(xbf, 128, projWt, 128, y, HID,
                                     NNODE, 256, 128);
  node_prep<<<(2 * NNODE * 64) / 256, 256, 0, stream>>>(
      y, proj_b, proj_g, proj_be, h_bf, offs, sW, Arel, Vv, ebias);

  // main-GEMM grid: XCD-remapped 1D; MT=313, NT=14, chunk=40 -> 8*40*14 = 4480
  const int MT = (NNODE + 127) / 128, NT = KCAT / 128;
  const int chunk = (MT + 7) / 8;
  const int nblk = 8 * chunk * NT;
  for (int l = 0; l < 3; ++l) {
    gemm32<0><<<nblk, 256, 0, stream>>>(h_bf, HID,
                                        WallT + (size_t)l * KCAT * 256, 256,
                                        z, KCAT, NNODE, KCAT, 256);
    agg_epilogue<<<(NNODE * 64 + 255) / 256, 256, 0, stream>>>(
        z, offs, sSrc, ebias, convb + l * HID, ln_g + l * HID, ln_b + l * HID,
        h_bf, (l == 2) ? outp : nullptr);
  }
}